// Round 10
// baseline (198.502 us; speedup 1.0000x reference)
//
#include <hip/hip_runtime.h>
#include <hip/hip_bf16.h>
#include <math.h>

// Problem constants
#define S 768
#define E 512
#define H 8
#define DK 64
#define TOPK 384

typedef short bf16x8 __attribute__((ext_vector_type(8)));
typedef float f32x4 __attribute__((ext_vector_type(4)));
typedef unsigned short ushort_t;

// ---------------------------------------------------------------------------
// fp32 <-> bf16 split helpers (round-to-nearest-even)
// ---------------------------------------------------------------------------
__device__ __forceinline__ unsigned short f2bf(float x) {
  unsigned u = __float_as_uint(x);
  unsigned r = u + 0x7FFFu + ((u >> 16) & 1u);
  return (unsigned short)(r >> 16);
}
__device__ __forceinline__ float bf2f(unsigned short h) {
  return __uint_as_float(((unsigned)h) << 16);
}
__device__ __forceinline__ void split1(float x, unsigned short& h, unsigned short& l) {
  h = f2bf(x);
  l = f2bf(x - bf2f(h));
}

// 3-term fp32-accurate bf16 MFMA: D += A*B with A=ah+al, B=bh+bl (drop al*bl)
__device__ __forceinline__ void mfma3(f32x4& d, bf16x8 ah, bf16x8 al,
                                      bf16x8 bh, bf16x8 bl) {
  d = __builtin_amdgcn_mfma_f32_16x16x32_bf16(ah, bh, d, 0, 0, 0);
  d = __builtin_amdgcn_mfma_f32_16x16x32_bf16(ah, bl, d, 0, 0, 0);
  d = __builtin_amdgcn_mfma_f32_16x16x32_bf16(al, bh, d, 0, 0, 0);
}

__device__ __forceinline__ bf16x8 ldfrag(const unsigned short* p) {
  return *reinterpret_cast<const bf16x8*>(p);
}

// ---------------------------------------------------------------------------
// prep: split x -> Xhi/Xlo; transpose+split W[k][n] -> WT[n][k] hi/lo.
// seg: 0=x(no transpose) 1=Wq 2=Wk 3=Wv 4=iqW 5=ikW 6=wpW(pad n to 64) 7=Wo
// ---------------------------------------------------------------------------
struct PrepTab {
  const float* src[8];
  unsigned short* hi[8];
  unsigned short* lo[8];
};

__global__ __launch_bounds__(256) void prep_kernel(PrepTab t) {
  const int seg = blockIdx.z;
  const int rows = (seg == 0) ? 768 : 512;
  const int cols = (seg == 5) ? 64 : ((seg == 6) ? 8 : 512);
  const int tx = (seg == 6) ? 2 : ((cols + 31) >> 5);   // seg6: cover 64 padded n-rows
  const int ty = rows >> 5;
  if ((int)blockIdx.x >= tx || (int)blockIdx.y >= ty) return;
  const int r0 = blockIdx.y * 32, c0 = blockIdx.x * 32;
  const int tid = threadIdx.x;
  const int rl = tid >> 3, c4 = (tid & 7) << 2;
  const float* src = t.src[seg];
  if (seg == 0) {
    float4 v = *(const float4*)(src + (size_t)(r0 + rl) * cols + c0 + c4);
    unsigned short h[4], l[4];
    split1(v.x, h[0], l[0]); split1(v.y, h[1], l[1]);
    split1(v.z, h[2], l[2]); split1(v.w, h[3], l[3]);
    size_t off = (size_t)(r0 + rl) * cols + c0 + c4;
    *(ushort4*)(t.hi[seg] + off) = make_ushort4(h[0], h[1], h[2], h[3]);
    *(ushort4*)(t.lo[seg] + off) = make_ushort4(l[0], l[1], l[2], l[3]);
  } else {
    __shared__ float ts[32][33];
    #pragma unroll
    for (int j = 0; j < 4; ++j) {
      int c = c4 + j;
      ts[rl][c] = (c0 + c < cols) ? src[(size_t)(r0 + rl) * cols + c0 + c] : 0.0f;
    }
    __syncthreads();
    float v0 = ts[c4 + 0][rl], v1 = ts[c4 + 1][rl];
    float v2 = ts[c4 + 2][rl], v3 = ts[c4 + 3][rl];
    unsigned short h[4], l[4];
    split1(v0, h[0], l[0]); split1(v1, h[1], l[1]);
    split1(v2, h[2], l[2]); split1(v3, h[3], l[3]);
    size_t off = (size_t)(c0 + rl) * 512 + r0 + c4;
    *(ushort4*)(t.hi[seg] + off) = make_ushort4(h[0], h[1], h[2], h[3]);
    *(ushort4*)(t.lo[seg] + off) = make_ushort4(l[0], l[1], l[2], l[3]);
  }
}

// ---------------------------------------------------------------------------
// Fused projections via MFMA, 32x64 tile per block (4 waves: 2 m-halves x
// 2 n-halves of 16x32). Grid (34, 24) = 816 blocks for occupancy.
// Epilogue routes per segment, emitting bf16 hi/lo layouts for downstream
// MFMA consumers: Q row-major, K [h][t][d], V^T [h][d][t], QI, KI. WI fp32.
// ---------------------------------------------------------------------------
struct ProjTab {
  const unsigned short* whi[6];
  const unsigned short* wlo[6];
  const float* bias[6];
};

__global__ __launch_bounds__(256) void proj_mfma_kernel(
    const unsigned short* __restrict__ Xhi, const unsigned short* __restrict__ Xlo,
    ProjTab pt,
    unsigned short* __restrict__ Qhi, unsigned short* __restrict__ Qlo,
    unsigned short* __restrict__ Khi, unsigned short* __restrict__ Klo,
    unsigned short* __restrict__ VThi, unsigned short* __restrict__ VTlo,
    unsigned short* __restrict__ QIhi, unsigned short* __restrict__ QIlo,
    unsigned short* __restrict__ KIhi, unsigned short* __restrict__ KIlo,
    float* __restrict__ WI) {
  const int bx = blockIdx.x;
  int seg, nt;
  if (bx < 32) { seg = bx >> 3; nt = bx & 7; }
  else         { seg = 4 + (bx - 32); nt = 0; }
  const int m0 = blockIdx.y * 32;
  const int tid = threadIdx.x;
  const int lane = tid & 63;
  const int wave = tid >> 6;
  const int mq = (wave >> 1) << 4;     // 0 or 16
  const int nqb = (wave & 1) << 5;     // 0 or 32
  const int l15 = lane & 15;
  const int q8 = (lane >> 4) << 3;
  const int q4 = (lane >> 4) << 2;
  const unsigned short* Whi = pt.whi[seg];
  const unsigned short* Wlo = pt.wlo[seg];
  const size_t arow = (size_t)(m0 + mq + l15) * 512;
  const int n0 = nt * 64 + nqb;
  const size_t brow0 = (size_t)(n0 + l15) * 512;
  const size_t brow1 = (size_t)(n0 + 16 + l15) * 512;

  f32x4 acc[2] = {};
  for (int k0 = 0; k0 < 512; k0 += 32) {
    const int ko = k0 + q8;
    bf16x8 ah = ldfrag(Xhi + arow + ko);
    bf16x8 al = ldfrag(Xlo + arow + ko);
    bf16x8 bh0 = ldfrag(Whi + brow0 + ko);
    bf16x8 bl0 = ldfrag(Wlo + brow0 + ko);
    bf16x8 bh1 = ldfrag(Whi + brow1 + ko);
    bf16x8 bl1 = ldfrag(Wlo + brow1 + ko);
    mfma3(acc[0], ah, al, bh0, bl0);
    mfma3(acc[1], ah, al, bh1, bl1);
  }

  const float* bias = pt.bias[seg];
  #pragma unroll
  for (int ntt = 0; ntt < 2; ++ntt) {
    const int nloc = n0 + ntt * 16 + l15;
    const float bv = (seg == 5 && nloc >= 8) ? 0.0f : bias[nloc];
    #pragma unroll
    for (int r = 0; r < 4; ++r) {
      const int m = m0 + mq + q4 + r;
      const float v = acc[ntt][r] + bv;
      unsigned short h16, l16;
      if (seg == 0) {
        split1(v, h16, l16);
        Qhi[(size_t)m * 512 + nloc] = h16;
        Qlo[(size_t)m * 512 + nloc] = l16;
      } else if (seg == 1) {
        const int hh = nloc >> 6, dd = nloc & 63;
        split1(v, h16, l16);
        Khi[((size_t)hh * S + m) * 64 + dd] = h16;
        Klo[((size_t)hh * S + m) * 64 + dd] = l16;
      } else if (seg == 2) {
        const int hh = nloc >> 6, dd = nloc & 63;
        split1(v, h16, l16);
        VThi[((size_t)hh * 64 + dd) * S + m] = h16;
        VTlo[((size_t)hh * 64 + dd) * S + m] = l16;
      } else if (seg == 3) {
        split1(v, h16, l16);
        QIhi[(size_t)m * 512 + nloc] = h16;
        QIlo[(size_t)m * 512 + nloc] = l16;
      } else if (seg == 4) {
        split1(v, h16, l16);
        KIhi[(size_t)m * 64 + nloc] = h16;
        KIlo[(size_t)m * 64 + nloc] = l16;
      } else {
        if (nloc < 8) WI[(size_t)m * 8 + nloc] = v;
      }
    }
  }
}

// ---------------------------------------------------------------------------
// Indexer via MFMA: ISC[s][t] = sum_h relu(dot64(QI[s,h],KI[t])) * WI[s][h].
// 32x64 tile, grid (12, 24) = 288 blocks x 4 waves.
// ---------------------------------------------------------------------------
__global__ __launch_bounds__(256) void indexer_mfma_kernel(
    const unsigned short* __restrict__ QIhi, const unsigned short* __restrict__ QIlo,
    const unsigned short* __restrict__ KIhi, const unsigned short* __restrict__ KIlo,
    const float* __restrict__ WI, float* __restrict__ ISC) {
  __shared__ float wis[32][8];
  const int s0 = blockIdx.y * 32, t0 = blockIdx.x * 64;
  const int tid = threadIdx.x;
  const int lane = tid & 63;
  const int wave = tid >> 6;
  const int mq = (wave >> 1) << 4;
  const int nqb = (wave & 1) << 5;
  const int l15 = lane & 15;
  const int q8 = (lane >> 4) << 3;
  const int q4 = (lane >> 4) << 2;
  wis[tid >> 3][tid & 7] = WI[(size_t)(s0 + (tid >> 3)) * 8 + (tid & 7)];
  __syncthreads();

  const size_t arow = (size_t)(s0 + mq + l15) * 512;
  const size_t brow0 = (size_t)(t0 + nqb + l15) * 64;
  const size_t brow1 = (size_t)(t0 + nqb + 16 + l15) * 64;

  float accI[2][4] = {};
  for (int h = 0; h < H; ++h) {
    f32x4 d[2] = {};
    #pragma unroll
    for (int k0 = 0; k0 < 64; k0 += 32) {
      const int ka = h * 64 + k0 + q8;
      const int kb = k0 + q8;
      bf16x8 ah = ldfrag(QIhi + arow + ka);
      bf16x8 al = ldfrag(QIlo + arow + ka);
      bf16x8 bh0 = ldfrag(KIhi + brow0 + kb);
      bf16x8 bl0 = ldfrag(KIlo + brow0 + kb);
      bf16x8 bh1 = ldfrag(KIhi + brow1 + kb);
      bf16x8 bl1 = ldfrag(KIlo + brow1 + kb);
      mfma3(d[0], ah, al, bh0, bl0);
      mfma3(d[1], ah, al, bh1, bl1);
    }
    #pragma unroll
    for (int r = 0; r < 4; ++r) {
      const float w = wis[mq + q4 + r][h];
      accI[0][r] = fmaf(fmaxf(d[0][r], 0.0f), w, accI[0][r]);
      accI[1][r] = fmaf(fmaxf(d[1][r], 0.0f), w, accI[1][r]);
    }
  }
  #pragma unroll
  for (int ntt = 0; ntt < 2; ++ntt)
    #pragma unroll
    for (int r = 0; r < 4; ++r)
      ISC[(size_t)(s0 + mq + q4 + r) * S + t0 + nqb + ntt * 16 + l15] = accI[ntt][r];
}

// ---------------------------------------------------------------------------
// Top-k via exact radix select (selection set == jax.lax.top_k stable ties).
// Emits 768-bit mask, zeroes Sum.
// ---------------------------------------------------------------------------
__global__ __launch_bounds__(256) void topk_kernel(
    const float* __restrict__ ISC, unsigned* __restrict__ Mask,
    float* __restrict__ Sum) {
  __shared__ unsigned ordv[768];
  __shared__ int hist[256];
  __shared__ int gsum[16];
  __shared__ int sc[256];
  __shared__ unsigned mw[24];
  __shared__ unsigned sh_prefix;
  __shared__ int sh_R;
  const int s = blockIdx.x;
  const int tid = threadIdx.x;
  for (int i = tid; i < 768; i += 256) {
    float f = ISC[s * 768 + i] + 0.0f;
    unsigned u = __float_as_uint(f);
    ordv[i] = (u & 0x80000000u) ? ~u : (u | 0x80000000u);
  }
  if (tid < 24) mw[tid] = 0u;
  if (tid < H) Sum[tid * S + s] = 0.0f;
  if (tid == 0) { sh_prefix = 0u; sh_R = TOPK; }
  __syncthreads();
  for (int pass = 0; pass < 4; ++pass) {
    const int shift = 24 - pass * 8;
    hist[tid] = 0;
    __syncthreads();
    const unsigned pm = (pass == 0) ? 0u : (0xFFFFFFFFu << (shift + 8));
    const unsigned pref = sh_prefix;
    for (int i = tid; i < 768; i += 256) {
      unsigned o = ordv[i];
      if ((o & pm) == pref) atomicAdd(&hist[(o >> shift) & 255], 1);
    }
    __syncthreads();
    if (tid < 16) {
      int t = 0;
      #pragma unroll
      for (int k = 0; k < 16; ++k) t += hist[tid * 16 + k];
      gsum[tid] = t;
    }
    __syncthreads();
    if (tid == 0) {
      int R = sh_R;
      int G = 0;
      int g = 15;
      for (; g > 0; --g) {
        if (G + gsum[g] >= R) break;
        G += gsum[g];
      }
      int b = 15;
      for (; b > 0; --b) {
        int c = hist[g * 16 + b];
        if (G + c >= R) break;
        G += c;
      }
      sh_prefix = sh_prefix | ((unsigned)(g * 16 + b) << shift);
      sh_R = R - G;
    }
    __syncthreads();
  }
  const unsigned thr = sh_prefix;
  const int need_eq = sh_R;
  const int base = tid * 3;
  unsigned o0 = ordv[base], o1 = ordv[base + 1], o2 = ordv[base + 2];
  int c = (o0 == thr) + (o1 == thr) + (o2 == thr);
  sc[tid] = c;
  __syncthreads();
  for (int off = 1; off < 256; off <<= 1) {
    int v = (tid >= off) ? sc[tid - off] : 0;
    __syncthreads();
    sc[tid] += v;
    __syncthreads();
  }
  int rank = sc[tid] - c;
  if (o0 > thr || (o0 == thr && rank < need_eq))
    atomicOr(&mw[base >> 5], 1u << (base & 31));
  if (o0 == thr) ++rank;
  if (o1 > thr || (o1 == thr && rank < need_eq))
    atomicOr(&mw[(base + 1) >> 5], 1u << ((base + 1) & 31));
  if (o1 == thr) ++rank;
  if (o2 > thr || (o2 == thr && rank < need_eq))
    atomicOr(&mw[(base + 2) >> 5], 1u << ((base + 2) & 31));
  __syncthreads();
  if (tid < 24) Mask[s * 24 + tid] = mw[tid];
}

// ---------------------------------------------------------------------------
// Fused masked attention via MFMA. Block = (ks 0..3, 32-s tile, h), 4 waves.
// Per 32-t chunk: scores (2x2 16x16 MFMA quadrants, 3-term split), mask+exp
// on D-frags, P -> LDS bf16 hi/lo (pitch 40), row-sum shuffle-reduce,
// PV = P x V^T via MFMA (V^T [h][d][t], 3-term). No max-subtraction
// (|score| <~ 1.5 by construction).
// ---------------------------------------------------------------------------
__global__ __launch_bounds__(256) void sattn_kernel(
    const unsigned short* __restrict__ Qhi, const unsigned short* __restrict__ Qlo,
    const unsigned short* __restrict__ Khi, const unsigned short* __restrict__ Klo,
    const unsigned short* __restrict__ VThi, const unsigned short* __restrict__ VTlo,
    const unsigned* __restrict__ Mask, float* __restrict__ Opart,
    float* __restrict__ Sum) {
  __shared__ __align__(16) unsigned short Pshi[32][40];
  __shared__ __align__(16) unsigned short Pslo[32][40];
  __shared__ unsigned msk[32][6];
  __shared__ float rsumf[32];
  const int ks = blockIdx.x;
  const int s0 = blockIdx.y * 32;
  const int h  = blockIdx.z;
  const int tid = threadIdx.x;
  const int lane = tid & 63;
  const int wave = tid >> 6;
  const int l15 = lane & 15;
  const int q8 = (lane >> 4) << 3;
  const int q4 = (lane >> 4) << 2;
  const int mq = (wave >> 1) << 4;    // score rows / PV rows half
  const int nq = (wave & 1) << 4;     // score cols (16 of 32)
  const int db = (wave & 1) << 5;     // PV d-base (32 of 64)

  if (tid < 192) msk[tid & 31][tid >> 5] = Mask[(size_t)(s0 + (tid & 31)) * 24 + ks * 6 + (tid >> 5)];
  if (tid < 32) rsumf[tid] = 0.0f;
  __syncthreads();

  const size_t qrow = (size_t)(s0 + mq + l15) * 512 + h * 64;
  f32x4 oacc[2] = {};
  for (int ct = 0; ct < 6; ++ct) {
    const int tch = ks * 192 + ct * 32;
    // ---- scores (16x16 per wave) ----
    f32x4 d = {0.0f, 0.0f, 0.0f, 0.0f};
    const size_t krow = ((size_t)h * S + tch + nq + l15) * 64;
    #pragma unroll
    for (int k0 = 0; k0 < 64; k0 += 32) {
      bf16x8 ah = ldfrag(Qhi + qrow + k0 + q8);
      bf16x8 al = ldfrag(Qlo + qrow + k0 + q8);
      bf16x8 bh = ldfrag(Khi + krow + k0 + q8);
      bf16x8 bl = ldfrag(Klo + krow + k0 + q8);
      mfma3(d, ah, al, bh, bl);
    }
    // ---- mask + exp, write P to LDS, row-sum reduce ----
    const int tl = ct * 32 + nq + l15;         // t within the 192 chunk
    float e[4];
    #pragma unroll
    for (int r = 0; r < 4; ++r) {
      const int srow = mq + q4 + r;
      const unsigned w = msk[srow][tl >> 5];
      e[r] = ((w >> (tl & 31)) & 1u) ? __expf(d[r] * 0.125f) : 0.0f;
      unsigned short h16, l16;
      split1(e[r], h16, l16);
      Pshi[srow][nq + l15] = h16;
      Pslo[srow][nq + l15] = l16;
    }
    float v0 = e[0], v1 = e[1], v2 = e[2], v3 = e[3];
    #pragma unroll
    for (int off = 1; off < 16; off <<= 1) {
      v0 += __shfl_xor(v0, off);
      v1 += __shfl_xor(v1, off);
      v2 += __shfl_xor(v2, off);
      v3 += __shfl_xor(v3, off);
    }
    if (l15 == 0) {
      atomicAdd(&rsumf[mq + q4 + 0], v0);
      atomicAdd(&rsumf[mq + q4 + 1], v1);
      atomicAdd(&rsumf[mq + q4 + 2], v2);
      atomicAdd(&rsumf[mq + q4 + 3], v3);
    }
    __syncthreads();
    // ---- PV: O[32s x 64d] += P[32s x 32t] * V^T[t][d] ----
    bf16x8 pah = *(const bf16x8*)&Pshi[mq + l15][q8];
    bf16x8 pal = *(const bf16x8*)&Pslo[mq + l15][q8];
    #pragma unroll
    for (int dt = 0; dt < 2; ++dt) {
      const size_t vrow = ((size_t)h * 64 + db + dt * 16 + l15) * S + tch;
      bf16x8 vbh = ldfrag(VThi + vrow + q8);
      bf16x8 vbl = ldfrag(VTlo + vrow + q8);
      mfma3(oacc[dt], pah, pal, vbh, vbl);
    }
    __syncthreads();
  }
  float* Op = Opart + (size_t)ks * S * E;
  #pragma unroll
  for (int dt = 0; dt < 2; ++dt) {
    const int dd = db + dt * 16 + l15;
    #pragma unroll
    for (int r = 0; r < 4; ++r) {
      const int s = s0 + mq + q4 + r;
      Op[(size_t)s * E + h * DK + dd] = oacc[dt][r];
    }
  }
  if (tid < 32) atomicAdd(&Sum[(size_t)h * S + s0 + tid], rsumf[tid]);
}

// ---------------------------------------------------------------------------
// Combine PV partials, normalize, emit ATT as bf16 hi/lo.
// ---------------------------------------------------------------------------
__global__ __launch_bounds__(128) void combine_kernel(
    const float* __restrict__ Opart, const float* __restrict__ Sum,
    unsigned short* __restrict__ ATThi, unsigned short* __restrict__ ATTlo) {
  const int s = blockIdx.x;
  const int e = threadIdx.x * 4;
  const int h = e >> 6;
  const float inv = 1.0f / Sum[h * S + s];
  float4 o = {0.0f, 0.0f, 0.0f, 0.0f};
  #pragma unroll
  for (int x = 0; x < 4; ++x) {
    float4 p = *(const float4*)(Opart + (size_t)x * S * E + s * E + e);
    o.x += p.x; o.y += p.y; o.z += p.z; o.w += p.w;
  }
  o.x *= inv; o.y *= inv; o.z *= inv; o.w *= inv;
  unsigned short hh[4], ll[4];
  split1(o.x, hh[0], ll[0]); split1(o.y, hh[1], ll[1]);
  split1(o.z, hh[2], ll[2]); split1(o.w, hh[3], ll[3]);
  *(ushort4*)(ATThi + (size_t)s * 512 + e) = make_ushort4(hh[0], hh[1], hh[2], hh[3]);
  *(ushort4*)(ATTlo + (size_t)s * 512 + e) = make_ushort4(ll[0], ll[1], ll[2], ll[3]);
}

// ---------------------------------------------------------------------------
// Output projection via MFMA: block = 16m x 64n (4 waves, 16x16 each).
// Grid (8, 48) = 384 blocks x 4 waves.
// ---------------------------------------------------------------------------
__global__ __launch_bounds__(256) void out_mfma_kernel(
    const unsigned short* __restrict__ Ahi, const unsigned short* __restrict__ Alo,
    const unsigned short* __restrict__ WoThi, const unsigned short* __restrict__ WoTlo,
    const float* __restrict__ bo, float* __restrict__ out) {
  const int tid = threadIdx.x;
  const int lane = tid & 63;
  const int wave = tid >> 6;
  const int m0 = blockIdx.y * 16;
  const int n0 = blockIdx.x * 64 + wave * 16;
  const int l15 = lane & 15;
  const int q8 = (lane >> 4) << 3;
  const int q4 = (lane >> 4) << 2;
  const size_t arow = (size_t)(m0 + l15) * 512;
  const size_t brow = (size_t)(n0 + l15) * 512;
  f32x4 acc = {};
  for (int k0 = 0; k0 < 512; k0 += 32) {
    const int ko = k0 + q8;
    bf16x8 ah = ldfrag(Ahi + arow + ko);
    bf16x8 al = ldfrag(Alo + arow + ko);
    bf16x8 bh = ldfrag(WoThi + brow + ko);
    bf16x8 bl = ldfrag(WoTlo + brow + ko);
    mfma3(acc, ah, al, bh, bl);
  }
  const int n = n0 + l15;
  const float bv = bo[n];
  #pragma unroll
  for (int r = 0; r < 4; ++r)
    out[(size_t)(m0 + q4 + r) * 512 + n] = acc[r] + bv;
}

// ---------------------------------------------------------------------------
// Launch
// ---------------------------------------------------------------------------
extern "C" void kernel_launch(void* const* d_in, const int* in_sizes, int n_in,
                              void* d_out, int out_size, void* d_ws, size_t ws_size,
                              hipStream_t stream) {
  const float* x    = (const float*)d_in[0];
  const float* Wq   = (const float*)d_in[1];
  const float* bq   = (const float*)d_in[2];
  const float* Wk   = (const float*)d_in[3];
  const float* bk   = (const float*)d_in[4];
  const float* Wv   = (const float*)d_in[5];
  const float* bv   = (const float*)d_in[6];
  const float* Wo   = (const float*)d_in[7];
  const float* bo   = (const float*)d_in[8];
  const float* iqW  = (const float*)d_in[9];
  const float* iqb  = (const float*)d_in[10];
  const float* ikW  = (const float*)d_in[11];
  const float* ikb  = (const float*)d_in[12];
  const float* wpW  = (const float*)d_in[13];
  const float* wpb  = (const float*)d_in[14];

  float* ws = (float*)d_ws;
  float* WI   = ws;                         // S*H fp32
  float* ISC  = WI + S * H;                 // S*S fp32
  unsigned* Mask = (unsigned*)(ISC + S * S);  // S*24
  float* Sum  = (float*)(Mask + S * 24);    // H*S
  float* Opart = Sum + H * S;               // 4*S*E fp32
  unsigned short* u = (unsigned short*)(Opart + 4 * S * E);
  unsigned short* Xhi  = u;             u += S * E;
  unsigned short* Xlo  = u;             u += S * E;
  unsigned short* Qhi  = u;             u += S * E;
  unsigned short* Qlo  = u;             u += S * E;
  unsigned short* Khi  = u;             u += S * E;
  unsigned short* Klo  = u;             u += S * E;
  unsigned short* VThi = u;             u += S * E;
  unsigned short* VTlo = u;             u += S * E;
  unsigned short* QIhi = u;             u += S * E;
  unsigned short* QIlo = u;             u += S * E;
  unsigned short* KIhi = u;             u += S * DK;
  unsigned short* KIlo = u;             u += S * DK;
  unsigned short* ATThi = u;            u += S * E;
  unsigned short* ATTlo = u;            u += S * E;
  unsigned short* WTq_hi = u;           u += E * E;
  unsigned short* WTk_hi = u;           u += E * E;
  unsigned short* WTv_hi = u;           u += E * E;
  unsigned short* WTiq_hi = u;          u += E * E;
  unsigned short* WTik_hi = u;          u += 64 * E;
  unsigned short* WTwp_hi = u;          u += 64 * E;
  unsigned short* WTo_hi = u;           u += E * E;
  unsigned short* WTq_lo = u;           u += E * E;
  unsigned short* WTk_lo = u;           u += E * E;
  unsigned short* WTv_lo = u;           u += E * E;
  unsigned short* WTiq_lo = u;          u += E * E;
  unsigned short* WTik_lo = u;          u += 64 * E;
  unsigned short* WTwp_lo = u;          u += 64 * E;
  unsigned short* WTo_lo = u;           u += E * E;

  PrepTab prep;
  prep.src[0] = x;    prep.hi[0] = Xhi;     prep.lo[0] = Xlo;
  prep.src[1] = Wq;   prep.hi[1] = WTq_hi;  prep.lo[1] = WTq_lo;
  prep.src[2] = Wk;   prep.hi[2] = WTk_hi;  prep.lo[2] = WTk_lo;
  prep.src[3] = Wv;   prep.hi[3] = WTv_hi;  prep.lo[3] = WTv_lo;
  prep.src[4] = iqW;  prep.hi[4] = WTiq_hi; prep.lo[4] = WTiq_lo;
  prep.src[5] = ikW;  prep.hi[5] = WTik_hi; prep.lo[5] = WTik_lo;
  prep.src[6] = wpW;  prep.hi[6] = WTwp_hi; prep.lo[6] = WTwp_lo;
  prep.src[7] = Wo;   prep.hi[7] = WTo_hi;  prep.lo[7] = WTo_lo;

  ProjTab pt;
  pt.whi[0] = WTq_hi;  pt.wlo[0] = WTq_lo;  pt.bias[0] = bq;
  pt.whi[1] = WTk_hi;  pt.wlo[1] = WTk_lo;  pt.bias[1] = bk;
  pt.whi[2] = WTv_hi;  pt.wlo[2] = WTv_lo;  pt.bias[2] = bv;
  pt.whi[3] = WTiq_hi; pt.wlo[3] = WTiq_lo; pt.bias[3] = iqb;
  pt.whi[4] = WTik_hi; pt.wlo[4] = WTik_lo; pt.bias[4] = ikb;
  pt.whi[5] = WTwp_hi; pt.wlo[5] = WTwp_lo; pt.bias[5] = wpb;

  // 1) split x + transpose/split all weight matrices
  prep_kernel<<<dim3(16, 24, 8), dim3(256), 0, stream>>>(prep);
  // 2) all 6 projections via MFMA: 34 x 24 = 816 blocks
  proj_mfma_kernel<<<dim3(34, S / 32), dim3(256), 0, stream>>>(
      Xhi, Xlo, pt, Qhi, Qlo, Khi, Klo, VThi, VTlo, QIhi, QIlo, KIhi, KIlo, WI);
  // 3) indexer scores via MFMA: 12 x 24 = 288 blocks
  indexer_mfma_kernel<<<dim3(S / 64, S / 32), dim3(256), 0, stream>>>(
      QIhi, QIlo, KIhi, KIlo, WI, ISC);
  // 4) top-k per row (radix select; zeroes Sum)
  topk_kernel<<<dim3(S), dim3(256), 0, stream>>>(ISC, Mask, Sum);
  // 5) fused masked attention via MFMA: (4 chunks, 24 s-tiles, 8 h) = 768 blocks
  sattn_kernel<<<dim3(4, S / 32, H), dim3(256), 0, stream>>>(
      Qhi, Qlo, Khi, Klo, VThi, VTlo, Mask, Opart, Sum);
  // 6) combine + normalize + cast ATT to bf16 hi/lo
  combine_kernel<<<dim3(S), dim3(128), 0, stream>>>(Opart, Sum, ATThi, ATTlo);
  // 7) output projection via MFMA: (8 n64, 48 m16) = 384 blocks
  out_mfma_kernel<<<dim3(8, 48), dim3(256), 0, stream>>>(
      ATThi, ATTlo, WTo_hi, WTo_lo, bo, (float*)d_out);
}

// Round 11
// 186.249 us; speedup vs baseline: 1.0658x; 1.0658x over previous
//
#include <hip/hip_runtime.h>
#include <hip/hip_bf16.h>
#include <math.h>

// Problem constants
#define S 768
#define E 512
#define H 8
#define DK 64
#define TOPK 384

typedef short bf16x8 __attribute__((ext_vector_type(8)));
typedef float f32x4 __attribute__((ext_vector_type(4)));

// ---------------------------------------------------------------------------
// fp32 <-> bf16 split helpers (round-to-nearest-even)
// ---------------------------------------------------------------------------
__device__ __forceinline__ unsigned short f2bf(float x) {
  unsigned u = __float_as_uint(x);
  unsigned r = u + 0x7FFFu + ((u >> 16) & 1u);
  return (unsigned short)(r >> 16);
}
__device__ __forceinline__ float bf2f(unsigned short h) {
  return __uint_as_float(((unsigned)h) << 16);
}
__device__ __forceinline__ void split1(float x, unsigned short& h, unsigned short& l) {
  h = f2bf(x);
  l = f2bf(x - bf2f(h));
}

// 3-term fp32-accurate bf16 MFMA: D += A*B with A=ah+al, B=bh+bl (drop al*bl)
__device__ __forceinline__ void mfma3(f32x4& d, bf16x8 ah, bf16x8 al,
                                      bf16x8 bh, bf16x8 bl) {
  d = __builtin_amdgcn_mfma_f32_16x16x32_bf16(ah, bh, d, 0, 0, 0);
  d = __builtin_amdgcn_mfma_f32_16x16x32_bf16(ah, bl, d, 0, 0, 0);
  d = __builtin_amdgcn_mfma_f32_16x16x32_bf16(al, bh, d, 0, 0, 0);
}

__device__ __forceinline__ bf16x8 ldfrag(const unsigned short* p) {
  return *reinterpret_cast<const bf16x8*>(p);
}

// ---------------------------------------------------------------------------
// prep: split x -> Xhi/Xlo; transpose+split W[k][n] -> WT[n][k] hi/lo.
// seg: 0=x(no transpose) 1=Wq 2=Wk 3=Wv 4=iqW 5=ikW 6=wpW(pad n to 64) 7=Wo
// ---------------------------------------------------------------------------
struct PrepTab {
  const float* src[8];
  unsigned short* hi[8];
  unsigned short* lo[8];
};

__global__ __launch_bounds__(256) void prep_kernel(PrepTab t) {
  const int seg = blockIdx.z;
  const int rows = (seg == 0) ? 768 : 512;
  const int cols = (seg == 5) ? 64 : ((seg == 6) ? 8 : 512);
  const int tx = (seg == 6) ? 2 : ((cols + 31) >> 5);
  const int ty = rows >> 5;
  if ((int)blockIdx.x >= tx || (int)blockIdx.y >= ty) return;
  const int r0 = blockIdx.y * 32, c0 = blockIdx.x * 32;
  const int tid = threadIdx.x;
  const int rl = tid >> 3, c4 = (tid & 7) << 2;
  const float* src = t.src[seg];
  if (seg == 0) {
    float4 v = *(const float4*)(src + (size_t)(r0 + rl) * cols + c0 + c4);
    unsigned short h[4], l[4];
    split1(v.x, h[0], l[0]); split1(v.y, h[1], l[1]);
    split1(v.z, h[2], l[2]); split1(v.w, h[3], l[3]);
    size_t off = (size_t)(r0 + rl) * cols + c0 + c4;
    *(ushort4*)(t.hi[seg] + off) = make_ushort4(h[0], h[1], h[2], h[3]);
    *(ushort4*)(t.lo[seg] + off) = make_ushort4(l[0], l[1], l[2], l[3]);
  } else {
    __shared__ float ts[32][33];
    #pragma unroll
    for (int j = 0; j < 4; ++j) {
      int c = c4 + j;
      ts[rl][c] = (c0 + c < cols) ? src[(size_t)(r0 + rl) * cols + c0 + c] : 0.0f;
    }
    __syncthreads();
    float v0 = ts[c4 + 0][rl], v1 = ts[c4 + 1][rl];
    float v2 = ts[c4 + 2][rl], v3 = ts[c4 + 3][rl];
    unsigned short h[4], l[4];
    split1(v0, h[0], l[0]); split1(v1, h[1], l[1]);
    split1(v2, h[2], l[2]); split1(v3, h[3], l[3]);
    size_t off = (size_t)(c0 + rl) * 512 + r0 + c4;
    *(ushort4*)(t.hi[seg] + off) = make_ushort4(h[0], h[1], h[2], h[3]);
    *(ushort4*)(t.lo[seg] + off) = make_ushort4(l[0], l[1], l[2], l[3]);
  }
}

// ---------------------------------------------------------------------------
// Fused projections via MFMA, round-9 geometry: 64x64 tile per block, 4 waves
// = 2x2 quadrants of 32x32 (12 MFMA per 8 global loads per wave per k-step —
// the latency shield). Grid (34, 12). #pragma unroll 2 lets the compiler
// software-pipeline next k-step's loads under this step's MFMA burst.
// Epilogue emits bf16 hi/lo layouts for downstream MFMA consumers.
// ---------------------------------------------------------------------------
struct ProjTab {
  const unsigned short* whi[6];
  const unsigned short* wlo[6];
  const float* bias[6];
};

__global__ __launch_bounds__(256) void proj_mfma_kernel(
    const unsigned short* __restrict__ Xhi, const unsigned short* __restrict__ Xlo,
    ProjTab pt,
    unsigned short* __restrict__ Qhi, unsigned short* __restrict__ Qlo,
    unsigned short* __restrict__ Khi, unsigned short* __restrict__ Klo,
    unsigned short* __restrict__ VThi, unsigned short* __restrict__ VTlo,
    unsigned short* __restrict__ QIhi, unsigned short* __restrict__ QIlo,
    unsigned short* __restrict__ KIhi, unsigned short* __restrict__ KIlo,
    float* __restrict__ WI) {
  const int bx = blockIdx.x;
  int seg, nt;
  if (bx < 32) { seg = bx >> 3; nt = bx & 7; }
  else         { seg = 4 + (bx - 32); nt = 0; }
  const int m0 = blockIdx.y * 64;
  const int n0 = nt * 64;
  const int tid = threadIdx.x;
  const int lane = tid & 63;
  const int wave = tid >> 6;
  const int mq = (wave >> 1) << 5;        // 0 or 32
  const int nq = (wave & 1) << 5;         // 0 or 32
  const int l15 = lane & 15;
  const int q8 = (lane >> 4) << 3;
  const int q4 = (lane >> 4) << 2;
  const unsigned short* Whi = pt.whi[seg];
  const unsigned short* Wlo = pt.wlo[seg];

  const size_t arow0 = (size_t)(m0 + mq + l15) * 512;
  const size_t arow1 = (size_t)(m0 + mq + 16 + l15) * 512;
  const size_t brow0 = (size_t)(n0 + nq + l15) * 512;
  const size_t brow1 = (size_t)(n0 + nq + 16 + l15) * 512;

  f32x4 acc[2][2] = {};
  #pragma unroll 2
  for (int k0 = 0; k0 < 512; k0 += 32) {
    const int ko = k0 + q8;
    bf16x8 ah0 = ldfrag(Xhi + arow0 + ko);
    bf16x8 al0 = ldfrag(Xlo + arow0 + ko);
    bf16x8 ah1 = ldfrag(Xhi + arow1 + ko);
    bf16x8 al1 = ldfrag(Xlo + arow1 + ko);
    bf16x8 bh0 = ldfrag(Whi + brow0 + ko);
    bf16x8 bl0 = ldfrag(Wlo + brow0 + ko);
    bf16x8 bh1 = ldfrag(Whi + brow1 + ko);
    bf16x8 bl1 = ldfrag(Wlo + brow1 + ko);
    mfma3(acc[0][0], ah0, al0, bh0, bl0);
    mfma3(acc[0][1], ah0, al0, bh1, bl1);
    mfma3(acc[1][0], ah1, al1, bh0, bl0);
    mfma3(acc[1][1], ah1, al1, bh1, bl1);
  }

  const float* bias = pt.bias[seg];
  #pragma unroll
  for (int ntt = 0; ntt < 2; ++ntt) {
    const int nloc = n0 + nq + ntt * 16 + l15;
    const float bv = (seg == 5 && nloc >= 8) ? 0.0f : bias[nloc];
    #pragma unroll
    for (int mt = 0; mt < 2; ++mt) {
      #pragma unroll
      for (int r = 0; r < 4; ++r) {
        const int m = m0 + mq + mt * 16 + q4 + r;
        const float v = acc[mt][ntt][r] + bv;
        unsigned short h16, l16;
        if (seg == 0) {
          split1(v, h16, l16);
          Qhi[(size_t)m * 512 + nloc] = h16;
          Qlo[(size_t)m * 512 + nloc] = l16;
        } else if (seg == 1) {
          const int hh = nloc >> 6, dd = nloc & 63;
          split1(v, h16, l16);
          Khi[((size_t)hh * S + m) * 64 + dd] = h16;
          Klo[((size_t)hh * S + m) * 64 + dd] = l16;
        } else if (seg == 2) {
          const int hh = nloc >> 6, dd = nloc & 63;
          split1(v, h16, l16);
          VThi[((size_t)hh * 64 + dd) * S + m] = h16;
          VTlo[((size_t)hh * 64 + dd) * S + m] = l16;
        } else if (seg == 3) {
          split1(v, h16, l16);
          QIhi[(size_t)m * 512 + nloc] = h16;
          QIlo[(size_t)m * 512 + nloc] = l16;
        } else if (seg == 4) {
          split1(v, h16, l16);
          KIhi[(size_t)m * 64 + nloc] = h16;
          KIlo[(size_t)m * 64 + nloc] = l16;
        } else {
          if (nloc < 8) WI[(size_t)m * 8 + nloc] = v;
        }
      }
    }
  }
}

// ---------------------------------------------------------------------------
// Indexer via MFMA: ISC[s][t] = sum_h relu(dot64(QI[s,h],KI[t])) * WI[s][h].
// 32x64 tile, grid (12, 24) = 288 blocks x 4 waves.
// ---------------------------------------------------------------------------
__global__ __launch_bounds__(256) void indexer_mfma_kernel(
    const unsigned short* __restrict__ QIhi, const unsigned short* __restrict__ QIlo,
    const unsigned short* __restrict__ KIhi, const unsigned short* __restrict__ KIlo,
    const float* __restrict__ WI, float* __restrict__ ISC) {
  __shared__ float wis[32][8];
  const int s0 = blockIdx.y * 32, t0 = blockIdx.x * 64;
  const int tid = threadIdx.x;
  const int lane = tid & 63;
  const int wave = tid >> 6;
  const int mq = (wave >> 1) << 4;
  const int nqb = (wave & 1) << 5;
  const int l15 = lane & 15;
  const int q8 = (lane >> 4) << 3;
  const int q4 = (lane >> 4) << 2;
  wis[tid >> 3][tid & 7] = WI[(size_t)(s0 + (tid >> 3)) * 8 + (tid & 7)];
  __syncthreads();

  const size_t arow = (size_t)(s0 + mq + l15) * 512;
  const size_t brow0 = (size_t)(t0 + nqb + l15) * 64;
  const size_t brow1 = (size_t)(t0 + nqb + 16 + l15) * 64;

  float accI[2][4] = {};
  #pragma unroll 2
  for (int h = 0; h < H; ++h) {
    f32x4 d[2] = {};
    #pragma unroll
    for (int k0 = 0; k0 < 64; k0 += 32) {
      const int ka = h * 64 + k0 + q8;
      const int kb = k0 + q8;
      bf16x8 ah = ldfrag(QIhi + arow + ka);
      bf16x8 al = ldfrag(QIlo + arow + ka);
      bf16x8 bh0 = ldfrag(KIhi + brow0 + kb);
      bf16x8 bl0 = ldfrag(KIlo + brow0 + kb);
      bf16x8 bh1 = ldfrag(KIhi + brow1 + kb);
      bf16x8 bl1 = ldfrag(KIlo + brow1 + kb);
      mfma3(d[0], ah, al, bh0, bl0);
      mfma3(d[1], ah, al, bh1, bl1);
    }
    #pragma unroll
    for (int r = 0; r < 4; ++r) {
      const float w = wis[mq + q4 + r][h];
      accI[0][r] = fmaf(fmaxf(d[0][r], 0.0f), w, accI[0][r]);
      accI[1][r] = fmaf(fmaxf(d[1][r], 0.0f), w, accI[1][r]);
    }
  }
  #pragma unroll
  for (int ntt = 0; ntt < 2; ++ntt)
    #pragma unroll
    for (int r = 0; r < 4; ++r)
      ISC[(size_t)(s0 + mq + q4 + r) * S + t0 + nqb + ntt * 16 + l15] = accI[ntt][r];
}

// ---------------------------------------------------------------------------
// Top-k via exact radix select (selection set == jax.lax.top_k stable ties).
// Emits 768-bit mask, zeroes Sum.
// ---------------------------------------------------------------------------
__global__ __launch_bounds__(256) void topk_kernel(
    const float* __restrict__ ISC, unsigned* __restrict__ Mask,
    float* __restrict__ Sum) {
  __shared__ unsigned ordv[768];
  __shared__ int hist[256];
  __shared__ int gsum[16];
  __shared__ int sc[256];
  __shared__ unsigned mw[24];
  __shared__ unsigned sh_prefix;
  __shared__ int sh_R;
  const int s = blockIdx.x;
  const int tid = threadIdx.x;
  for (int i = tid; i < 768; i += 256) {
    float f = ISC[s * 768 + i] + 0.0f;
    unsigned u = __float_as_uint(f);
    ordv[i] = (u & 0x80000000u) ? ~u : (u | 0x80000000u);
  }
  if (tid < 24) mw[tid] = 0u;
  if (tid < H) Sum[tid * S + s] = 0.0f;
  if (tid == 0) { sh_prefix = 0u; sh_R = TOPK; }
  __syncthreads();
  for (int pass = 0; pass < 4; ++pass) {
    const int shift = 24 - pass * 8;
    hist[tid] = 0;
    __syncthreads();
    const unsigned pm = (pass == 0) ? 0u : (0xFFFFFFFFu << (shift + 8));
    const unsigned pref = sh_prefix;
    for (int i = tid; i < 768; i += 256) {
      unsigned o = ordv[i];
      if ((o & pm) == pref) atomicAdd(&hist[(o >> shift) & 255], 1);
    }
    __syncthreads();
    if (tid < 16) {
      int t = 0;
      #pragma unroll
      for (int k = 0; k < 16; ++k) t += hist[tid * 16 + k];
      gsum[tid] = t;
    }
    __syncthreads();
    if (tid == 0) {
      int R = sh_R;
      int G = 0;
      int g = 15;
      for (; g > 0; --g) {
        if (G + gsum[g] >= R) break;
        G += gsum[g];
      }
      int b = 15;
      for (; b > 0; --b) {
        int c = hist[g * 16 + b];
        if (G + c >= R) break;
        G += c;
      }
      sh_prefix = sh_prefix | ((unsigned)(g * 16 + b) << shift);
      sh_R = R - G;
    }
    __syncthreads();
  }
  const unsigned thr = sh_prefix;
  const int need_eq = sh_R;
  const int base = tid * 3;
  unsigned o0 = ordv[base], o1 = ordv[base + 1], o2 = ordv[base + 2];
  int c = (o0 == thr) + (o1 == thr) + (o2 == thr);
  sc[tid] = c;
  __syncthreads();
  for (int off = 1; off < 256; off <<= 1) {
    int v = (tid >= off) ? sc[tid - off] : 0;
    __syncthreads();
    sc[tid] += v;
    __syncthreads();
  }
  int rank = sc[tid] - c;
  if (o0 > thr || (o0 == thr && rank < need_eq))
    atomicOr(&mw[base >> 5], 1u << (base & 31));
  if (o0 == thr) ++rank;
  if (o1 > thr || (o1 == thr && rank < need_eq))
    atomicOr(&mw[(base + 1) >> 5], 1u << ((base + 1) & 31));
  if (o1 == thr) ++rank;
  if (o2 > thr || (o2 == thr && rank < need_eq))
    atomicOr(&mw[(base + 2) >> 5], 1u << ((base + 2) & 31));
  __syncthreads();
  if (tid < 24) Mask[s * 24 + tid] = mw[tid];
}

// ---------------------------------------------------------------------------
// Fused masked attention via MFMA (verified correct in round 10).
// Block = (ks 0..3, 32-s tile, h), 4 waves.
// ---------------------------------------------------------------------------
__global__ __launch_bounds__(256) void sattn_kernel(
    const unsigned short* __restrict__ Qhi, const unsigned short* __restrict__ Qlo,
    const unsigned short* __restrict__ Khi, const unsigned short* __restrict__ Klo,
    const unsigned short* __restrict__ VThi, const unsigned short* __restrict__ VTlo,
    const unsigned* __restrict__ Mask, float* __restrict__ Opart,
    float* __restrict__ Sum) {
  __shared__ __align__(16) unsigned short Pshi[32][40];
  __shared__ __align__(16) unsigned short Pslo[32][40];
  __shared__ unsigned msk[32][6];
  __shared__ float rsumf[32];
  const int ks = blockIdx.x;
  const int s0 = blockIdx.y * 32;
  const int h  = blockIdx.z;
  const int tid = threadIdx.x;
  const int lane = tid & 63;
  const int wave = tid >> 6;
  const int l15 = lane & 15;
  const int q8 = (lane >> 4) << 3;
  const int q4 = (lane >> 4) << 2;
  const int mq = (wave >> 1) << 4;
  const int nq = (wave & 1) << 4;
  const int db = (wave & 1) << 5;

  if (tid < 192) msk[tid & 31][tid >> 5] = Mask[(size_t)(s0 + (tid & 31)) * 24 + ks * 6 + (tid >> 5)];
  if (tid < 32) rsumf[tid] = 0.0f;
  __syncthreads();

  const size_t qrow = (size_t)(s0 + mq + l15) * 512 + h * 64;
  f32x4 oacc[2] = {};
  for (int ct = 0; ct < 6; ++ct) {
    const int tch = ks * 192 + ct * 32;
    f32x4 d = {0.0f, 0.0f, 0.0f, 0.0f};
    const size_t krow = ((size_t)h * S + tch + nq + l15) * 64;
    #pragma unroll
    for (int k0 = 0; k0 < 64; k0 += 32) {
      bf16x8 ah = ldfrag(Qhi + qrow + k0 + q8);
      bf16x8 al = ldfrag(Qlo + qrow + k0 + q8);
      bf16x8 bh = ldfrag(Khi + krow + k0 + q8);
      bf16x8 bl = ldfrag(Klo + krow + k0 + q8);
      mfma3(d, ah, al, bh, bl);
    }
    const int tl = ct * 32 + nq + l15;
    float e[4];
    #pragma unroll
    for (int r = 0; r < 4; ++r) {
      const int srow = mq + q4 + r;
      const unsigned w = msk[srow][tl >> 5];
      e[r] = ((w >> (tl & 31)) & 1u) ? __expf(d[r] * 0.125f) : 0.0f;
      unsigned short h16, l16;
      split1(e[r], h16, l16);
      Pshi[srow][nq + l15] = h16;
      Pslo[srow][nq + l15] = l16;
    }
    float v0 = e[0], v1 = e[1], v2 = e[2], v3 = e[3];
    #pragma unroll
    for (int off = 1; off < 16; off <<= 1) {
      v0 += __shfl_xor(v0, off);
      v1 += __shfl_xor(v1, off);
      v2 += __shfl_xor(v2, off);
      v3 += __shfl_xor(v3, off);
    }
    if (l15 == 0) {
      atomicAdd(&rsumf[mq + q4 + 0], v0);
      atomicAdd(&rsumf[mq + q4 + 1], v1);
      atomicAdd(&rsumf[mq + q4 + 2], v2);
      atomicAdd(&rsumf[mq + q4 + 3], v3);
    }
    __syncthreads();
    bf16x8 pah = *(const bf16x8*)&Pshi[mq + l15][q8];
    bf16x8 pal = *(const bf16x8*)&Pslo[mq + l15][q8];
    #pragma unroll
    for (int dt = 0; dt < 2; ++dt) {
      const size_t vrow = ((size_t)h * 64 + db + dt * 16 + l15) * S + tch;
      bf16x8 vbh = ldfrag(VThi + vrow + q8);
      bf16x8 vbl = ldfrag(VTlo + vrow + q8);
      mfma3(oacc[dt], pah, pal, vbh, vbl);
    }
    __syncthreads();
  }
  float* Op = Opart + (size_t)ks * S * E;
  #pragma unroll
  for (int dt = 0; dt < 2; ++dt) {
    const int dd = db + dt * 16 + l15;
    #pragma unroll
    for (int r = 0; r < 4; ++r) {
      const int s = s0 + mq + q4 + r;
      Op[(size_t)s * E + h * DK + dd] = oacc[dt][r];
    }
  }
  if (tid < 32) atomicAdd(&Sum[(size_t)h * S + s0 + tid], rsumf[tid]);
}

// ---------------------------------------------------------------------------
// Combine PV partials, normalize, emit ATT as bf16 hi/lo.
// ---------------------------------------------------------------------------
__global__ __launch_bounds__(128) void combine_kernel(
    const float* __restrict__ Opart, const float* __restrict__ Sum,
    unsigned short* __restrict__ ATThi, unsigned short* __restrict__ ATTlo) {
  const int s = blockIdx.x;
  const int e = threadIdx.x * 4;
  const int h = e >> 6;
  const float inv = 1.0f / Sum[h * S + s];
  float4 o = {0.0f, 0.0f, 0.0f, 0.0f};
  #pragma unroll
  for (int x = 0; x < 4; ++x) {
    float4 p = *(const float4*)(Opart + (size_t)x * S * E + s * E + e);
    o.x += p.x; o.y += p.y; o.z += p.z; o.w += p.w;
  }
  o.x *= inv; o.y *= inv; o.z *= inv; o.w *= inv;
  unsigned short hh[4], ll[4];
  split1(o.x, hh[0], ll[0]); split1(o.y, hh[1], ll[1]);
  split1(o.z, hh[2], ll[2]); split1(o.w, hh[3], ll[3]);
  *(ushort4*)(ATThi + (size_t)s * 512 + e) = make_ushort4(hh[0], hh[1], hh[2], hh[3]);
  *(ushort4*)(ATTlo + (size_t)s * 512 + e) = make_ushort4(ll[0], ll[1], ll[2], ll[3]);
}

// ---------------------------------------------------------------------------
// Output projection via MFMA: block = 16m x 64n (4 waves, 16x16 each).
// ---------------------------------------------------------------------------
__global__ __launch_bounds__(256) void out_mfma_kernel(
    const unsigned short* __restrict__ Ahi, const unsigned short* __restrict__ Alo,
    const unsigned short* __restrict__ WoThi, const unsigned short* __restrict__ WoTlo,
    const float* __restrict__ bo, float* __restrict__ out) {
  const int tid = threadIdx.x;
  const int lane = tid & 63;
  const int wave = tid >> 6;
  const int m0 = blockIdx.y * 16;
  const int n0 = blockIdx.x * 64 + wave * 16;
  const int l15 = lane & 15;
  const int q8 = (lane >> 4) << 3;
  const int q4 = (lane >> 4) << 2;
  const size_t arow = (size_t)(m0 + l15) * 512;
  const size_t brow = (size_t)(n0 + l15) * 512;
  f32x4 acc = {};
  #pragma unroll 2
  for (int k0 = 0; k0 < 512; k0 += 32) {
    const int ko = k0 + q8;
    bf16x8 ah = ldfrag(Ahi + arow + ko);
    bf16x8 al = ldfrag(Alo + arow + ko);
    bf16x8 bh = ldfrag(WoThi + brow + ko);
    bf16x8 bl = ldfrag(WoTlo + brow + ko);
    mfma3(acc, ah, al, bh, bl);
  }
  const int n = n0 + l15;
  const float bv = bo[n];
  #pragma unroll
  for (int r = 0; r < 4; ++r)
    out[(size_t)(m0 + q4 + r) * 512 + n] = acc[r] + bv;
}

// ---------------------------------------------------------------------------
// Launch
// ---------------------------------------------------------------------------
extern "C" void kernel_launch(void* const* d_in, const int* in_sizes, int n_in,
                              void* d_out, int out_size, void* d_ws, size_t ws_size,
                              hipStream_t stream) {
  const float* x    = (const float*)d_in[0];
  const float* Wq   = (const float*)d_in[1];
  const float* bq   = (const float*)d_in[2];
  const float* Wk   = (const float*)d_in[3];
  const float* bk   = (const float*)d_in[4];
  const float* Wv   = (const float*)d_in[5];
  const float* bv   = (const float*)d_in[6];
  const float* Wo   = (const float*)d_in[7];
  const float* bo   = (const float*)d_in[8];
  const float* iqW  = (const float*)d_in[9];
  const float* iqb  = (const float*)d_in[10];
  const float* ikW  = (const float*)d_in[11];
  const float* ikb  = (const float*)d_in[12];
  const float* wpW  = (const float*)d_in[13];
  const float* wpb  = (const float*)d_in[14];

  float* ws = (float*)d_ws;
  float* WI   = ws;                         // S*H fp32
  float* ISC  = WI + S * H;                 // S*S fp32
  unsigned* Mask = (unsigned*)(ISC + S * S);  // S*24
  float* Sum  = (float*)(Mask + S * 24);    // H*S
  float* Opart = Sum + H * S;               // 4*S*E fp32
  unsigned short* u = (unsigned short*)(Opart + 4 * S * E);
  unsigned short* Xhi  = u;             u += S * E;
  unsigned short* Xlo  = u;             u += S * E;
  unsigned short* Qhi  = u;             u += S * E;
  unsigned short* Qlo  = u;             u += S * E;
  unsigned short* Khi  = u;             u += S * E;
  unsigned short* Klo  = u;             u += S * E;
  unsigned short* VThi = u;             u += S * E;
  unsigned short* VTlo = u;             u += S * E;
  unsigned short* QIhi = u;             u += S * E;
  unsigned short* QIlo = u;             u += S * E;
  unsigned short* KIhi = u;             u += S * DK;
  unsigned short* KIlo = u;             u += S * DK;
  unsigned short* ATThi = u;            u += S * E;
  unsigned short* ATTlo = u;            u += S * E;
  unsigned short* WTq_hi = u;           u += E * E;
  unsigned short* WTk_hi = u;           u += E * E;
  unsigned short* WTv_hi = u;           u += E * E;
  unsigned short* WTiq_hi = u;          u += E * E;
  unsigned short* WTik_hi = u;          u += 64 * E;
  unsigned short* WTwp_hi = u;          u += 64 * E;
  unsigned short* WTo_hi = u;           u += E * E;
  unsigned short* WTq_lo = u;           u += E * E;
  unsigned short* WTk_lo = u;           u += E * E;
  unsigned short* WTv_lo = u;           u += E * E;
  unsigned short* WTiq_lo = u;          u += E * E;
  unsigned short* WTik_lo = u;          u += 64 * E;
  unsigned short* WTwp_lo = u;          u += 64 * E;
  unsigned short* WTo_lo = u;           u += E * E;

  PrepTab prep;
  prep.src[0] = x;    prep.hi[0] = Xhi;     prep.lo[0] = Xlo;
  prep.src[1] = Wq;   prep.hi[1] = WTq_hi;  prep.lo[1] = WTq_lo;
  prep.src[2] = Wk;   prep.hi[2] = WTk_hi;  prep.lo[2] = WTk_lo;
  prep.src[3] = Wv;   prep.hi[3] = WTv_hi;  prep.lo[3] = WTv_lo;
  prep.src[4] = iqW;  prep.hi[4] = WTiq_hi; prep.lo[4] = WTiq_lo;
  prep.src[5] = ikW;  prep.hi[5] = WTik_hi; prep.lo[5] = WTik_lo;
  prep.src[6] = wpW;  prep.hi[6] = WTwp_hi; prep.lo[6] = WTwp_lo;
  prep.src[7] = Wo;   prep.hi[7] = WTo_hi;  prep.lo[7] = WTo_lo;

  ProjTab pt;
  pt.whi[0] = WTq_hi;  pt.wlo[0] = WTq_lo;  pt.bias[0] = bq;
  pt.whi[1] = WTk_hi;  pt.wlo[1] = WTk_lo;  pt.bias[1] = bk;
  pt.whi[2] = WTv_hi;  pt.wlo[2] = WTv_lo;  pt.bias[2] = bv;
  pt.whi[3] = WTiq_hi; pt.wlo[3] = WTiq_lo; pt.bias[3] = iqb;
  pt.whi[4] = WTik_hi; pt.wlo[4] = WTik_lo; pt.bias[4] = ikb;
  pt.whi[5] = WTwp_hi; pt.wlo[5] = WTwp_lo; pt.bias[5] = wpb;

  // 1) split x + transpose/split all weight matrices
  prep_kernel<<<dim3(16, 24, 8), dim3(256), 0, stream>>>(prep);
  // 2) all 6 projections via MFMA: 34 x 12 = 408 blocks (round-9 geometry)
  proj_mfma_kernel<<<dim3(34, S / 64), dim3(256), 0, stream>>>(
      Xhi, Xlo, pt, Qhi, Qlo, Khi, Klo, VThi, VTlo, QIhi, QIlo, KIhi, KIlo, WI);
  // 3) indexer scores via MFMA: 12 x 24 = 288 blocks
  indexer_mfma_kernel<<<dim3(S / 64, S / 32), dim3(256), 0, stream>>>(
      QIhi, QIlo, KIhi, KIlo, WI, ISC);
  // 4) top-k per row (radix select; zeroes Sum)
  topk_kernel<<<dim3(S), dim3(256), 0, stream>>>(ISC, Mask, Sum);
  // 5) fused masked attention via MFMA: (4 chunks, 24 s-tiles, 8 h)
  sattn_kernel<<<dim3(4, S / 32, H), dim3(256), 0, stream>>>(
      Qhi, Qlo, Khi, Klo, VThi, VTlo, Mask, Opart, Sum);
  // 6) combine + normalize + cast ATT to bf16 hi/lo
  combine_kernel<<<dim3(S), dim3(128), 0, stream>>>(Opart, Sum, ATThi, ATTlo);
  // 7) output projection via MFMA: (8 n64, 48 m16) = 384 blocks
  out_mfma_kernel<<<dim3(8, 48), dim3(256), 0, stream>>>(
      ATThi, ATTlo, WTo_hi, WTo_lo, bo, (float*)d_out);
}